// Round 1
// baseline (9321.200 us; speedup 1.0000x reference)
//
#include <hip/hip_runtime.h>

typedef unsigned short u16;
typedef unsigned int u32;
typedef unsigned long long u64;

#define N_ROWS 8192
#define H_DIM  2048
#define V_DIM  50257
#define BM 128
#define BN 128
#define BK 64
#define NTV 393          // ceil(V/128)
#define NT64 786         // ceil(V/64)
#define IGNORE_INDEX (-100)

typedef __attribute__((ext_vector_type(8))) short bf16x8;
typedef __attribute__((ext_vector_type(8))) u16   u16x8;
typedef __attribute__((ext_vector_type(4))) float f32x4;

__device__ __forceinline__ u16 f2bf(float f) {
  u32 u = __builtin_bit_cast(u32, f);
  u = (u + 0x7FFFu + ((u >> 16) & 1u)) >> 16;   // RNE; inputs are finite randoms
  return (u16)u;
}

// async global->LDS, 16B per lane. LDS dest must be linear in lane order.
__device__ __forceinline__ void gload_lds16(const void* g, void* l) {
  __builtin_amdgcn_global_load_lds(
      (const __attribute__((address_space(1))) u32*)(u64)g,
      (__attribute__((address_space(3))) u32*)(u32)(u64)l,
      16, 0, 0);
}

// ---------------- fp32 -> bf16 conversion (8 elems / thread) ----------------
__global__ __launch_bounds__(256) void cvt_f32_bf16(const float* __restrict__ in,
                                                    u16* __restrict__ out,
                                                    long long n) {
  long long i = ((long long)blockIdx.x * 256 + threadIdx.x) * 8;
  if (i >= n) return;
  const float4* p = (const float4*)(in + i);
  float4 a = p[0];
  float4 b = p[1];
  u16x8 o;
  o[0] = f2bf(a.x); o[1] = f2bf(a.y); o[2] = f2bf(a.z); o[3] = f2bf(a.w);
  o[4] = f2bf(b.x); o[5] = f2bf(b.y); o[6] = f2bf(b.z); o[7] = f2bf(b.w);
  *(u16x8*)(out + i) = o;
}

// ---------------- fused GEMM + partial CE ----------------
// C[n,v] = dot(X[n,:], W[v,:])  (both K-major: classic "B^T" NT GEMM)
// 128x128 tile, BK=64, 4 waves (2x2), each wave 64x64 via 4x4 x 16x16x32 MFMA.
// Epilogue: per (row, 64-col half tile) write partial max / sumexp; grab target logit.
__global__ __launch_bounds__(256) void gemm_ce(const u16* __restrict__ Xb,
                                               const u16* __restrict__ Wb,
                                               const int* __restrict__ target,
                                               float* __restrict__ pmax_out,
                                               float* __restrict__ psum_out,
                                               float* __restrict__ tgt_logit) {
  __shared__ u16 As[BM * BK];
  __shared__ u16 Bs[BN * BK];

  const int t    = threadIdx.x;
  const int w    = t >> 6;
  const int lane = t & 63;
  const int wr   = w >> 1, wc = w & 1;
  const int g    = lane >> 4, c = lane & 15;
  const int btile = blockIdx.x;            // v tile
  const int R0 = blockIdx.y * BM;
  const int C0 = btile * BN;

  f32x4 acc[4][4];
#pragma unroll
  for (int m = 0; m < 4; ++m)
#pragma unroll
    for (int n = 0; n < 4; ++n) acc[m][n] = (f32x4)0.f;

  for (int k0 = 0; k0 < H_DIM; k0 += BK) {
    // stage A tile (128x64 bf16 = 16KB): 4 x 16B per thread, linear in lane order
#pragma unroll
    for (int i = 0; i < 4; ++i) {
      int e = (i * 256 + t) * 8;           // element index in tile
      int row = e >> 6, kk = e & 63;
      gload_lds16(Xb + (size_t)(R0 + row) * H_DIM + k0 + kk, (void*)&As[e]);
    }
    // stage B tile (128x64 of W rows = output cols); clamp tail rows to V-1
#pragma unroll
    for (int i = 0; i < 4; ++i) {
      int e = (i * 256 + t) * 8;
      int row = e >> 6, kk = e & 63;
      int vg = C0 + row; if (vg > V_DIM - 1) vg = V_DIM - 1;
      gload_lds16(Wb + (size_t)vg * H_DIM + k0 + kk, (void*)&Bs[e]);
    }
    __syncthreads();   // compiler drains vmcnt before barrier -> tiles visible

#pragma unroll
    for (int h = 0; h < 2; ++h) {
      bf16x8 af[4], bfr[4];
#pragma unroll
      for (int m = 0; m < 4; ++m)
        af[m] = *(const bf16x8*)&As[(wr * 64 + m * 16 + c) * BK + h * 32 + g * 8];
#pragma unroll
      for (int n = 0; n < 4; ++n)
        bfr[n] = *(const bf16x8*)&Bs[(wc * 64 + n * 16 + c) * BK + h * 32 + g * 8];
#pragma unroll
      for (int m = 0; m < 4; ++m)
#pragma unroll
        for (int n = 0; n < 4; ++n)
          acc[m][n] = __builtin_amdgcn_mfma_f32_16x16x32_bf16(af[m], bfr[n], acc[m][n], 0, 0, 0);
    }
    __syncthreads();   // protect LDS from next iteration's staging
  }

  // ---- epilogue: per-row partial max & sumexp over this wave's 64 cols ----
  const float L2E = 1.4426950408889634f;
  const int wrow0 = R0 + wr * 64;
  const int wcol0 = C0 + wc * 64;
#pragma unroll
  for (int m = 0; m < 4; ++m) {
#pragma unroll
    for (int r = 0; r < 4; ++r) {
      int rowr = wrow0 + m * 16 + g * 4 + r;
      float vals[4];
      float vmax = -__builtin_inff();
#pragma unroll
      for (int n = 0; n < 4; ++n) {
        int col = wcol0 + n * 16 + c;
        float v = acc[m][n][r];
        vals[n] = (col < V_DIM) ? v : -__builtin_inff();
        vmax = fmaxf(vmax, vals[n]);
      }
#pragma unroll
      for (int ofs = 1; ofs < 16; ofs <<= 1) vmax = fmaxf(vmax, __shfl_xor(vmax, ofs));
      float vsum = 0.f;
#pragma unroll
      for (int n = 0; n < 4; ++n) vsum += exp2f((vals[n] - vmax) * L2E);  // -inf -> 0
#pragma unroll
      for (int ofs = 1; ofs < 16; ofs <<= 1) vsum += __shfl_xor(vsum, ofs);

      int tg = target[rowr];
      if (tg >= wcol0 && tg < wcol0 + 64) {
        int d = tg - wcol0;
        if ((d & 15) == c) tgt_logit[rowr] = acc[m][d >> 4][r];
      }
      if (c == 0) {
        size_t idx = (size_t)rowr * NT64 + (size_t)btile * 2 + wc;
        pmax_out[idx] = vmax;
        psum_out[idx] = vsum;
      }
    }
  }
}

// ---------------- stage 2: merge 786 partials per row -> per-row loss ----------------
__global__ __launch_bounds__(256) void reduce_rows(const float* __restrict__ pmax_in,
                                                   const float* __restrict__ psum_in,
                                                   const float* __restrict__ tgt_logit,
                                                   const int* __restrict__ target,
                                                   float* __restrict__ loss_row) {
  const float L2E = 1.4426950408889634f;
  const float LN2 = 0.6931471805599453f;
  int t = threadIdx.x;
  int lane = t & 63;
  int row = blockIdx.x * 4 + (t >> 6);

  float m = -__builtin_inff();
  float s = 0.f;
  for (int j = lane; j < NT64; j += 64) {
    float pm = pmax_in[(size_t)row * NT64 + j];
    float ps = psum_in[(size_t)row * NT64 + j];
    float nm = fmaxf(m, pm);
    s = s * exp2f((m - nm) * L2E) + ps * exp2f((pm - nm) * L2E);
    m = nm;
  }
#pragma unroll
  for (int ofs = 1; ofs < 64; ofs <<= 1) {
    float om = __shfl_xor(m, ofs);
    float os = __shfl_xor(s, ofs);
    float nm = fmaxf(m, om);
    s = s * exp2f((m - nm) * L2E) + os * exp2f((om - nm) * L2E);
    m = nm;
  }
  if (lane == 0) {
    int tg = target[row];
    float loss = 0.f;
    if (tg != IGNORE_INDEX) {
      float lse = m + log2f(s) * LN2;
      loss = lse - tgt_logit[row];
    }
    loss_row[row] = loss;
  }
}

// ---------------- stage 3: deterministic final sum ----------------
__global__ __launch_bounds__(256) void final_sum(const float* __restrict__ loss_row,
                                                 float* __restrict__ out) {
  __shared__ float sm[256];
  int t = threadIdx.x;
  float s = 0.f;
  for (int i = t; i < N_ROWS; i += 256) s += loss_row[i];
  sm[t] = s;
  __syncthreads();
  for (int st = 128; st > 0; st >>= 1) {
    if (t < st) sm[t] += sm[t + st];
    __syncthreads();
  }
  if (t == 0) out[0] = sm[0];
}

extern "C" void kernel_launch(void* const* d_in, const int* in_sizes, int n_in,
                              void* d_out, int out_size, void* d_ws, size_t ws_size,
                              hipStream_t stream) {
  const float* x  = (const float*)d_in[0];
  const float* wt = (const float*)d_in[1];
  const int* target = (const int*)d_in[2];
  float* out = (float*)d_out;

  char* ws = (char*)d_ws;
  size_t o = 0;
  u16* Xb = (u16*)(ws + o); o += (size_t)N_ROWS * H_DIM * 2;
  u16* Wb = (u16*)(ws + o); o += (size_t)V_DIM * H_DIM * 2;
  o = (o + 255) & ~(size_t)255;
  float* pmax = (float*)(ws + o); o += (size_t)N_ROWS * NT64 * 4;
  float* psum = (float*)(ws + o); o += (size_t)N_ROWS * NT64 * 4;
  float* tgt  = (float*)(ws + o); o += (size_t)N_ROWS * 4;
  float* lrow = (float*)(ws + o); o += (size_t)N_ROWS * 4;
  if (o > ws_size) return;   // workspace too small: fail loudly (validation will flag)

  long long nX = (long long)N_ROWS * H_DIM;
  long long nW = (long long)V_DIM * H_DIM;
  cvt_f32_bf16<<<(int)((nX + 2047) / 2048), 256, 0, stream>>>(x, Xb, nX);
  cvt_f32_bf16<<<(int)((nW + 2047) / 2048), 256, 0, stream>>>(wt, Wb, nW);

  dim3 grid(NTV, N_ROWS / BM);
  gemm_ce<<<grid, 256, 0, stream>>>(Xb, Wb, target, pmax, psum, tgt);

  reduce_rows<<<N_ROWS / 4, 256, 0, stream>>>(pmax, psum, tgt, target, lrow);
  final_sum<<<1, 256, 0, stream>>>(lrow, out);
}

// Round 2
// 2809.877 us; speedup vs baseline: 3.3173x; 3.3173x over previous
//
#include <hip/hip_runtime.h>

typedef unsigned short u16;
typedef unsigned int u32;
typedef unsigned long long u64;

#define N_ROWS 8192
#define H_DIM  2048
#define V_DIM  50257
#define BM 128
#define BN 128
#define BK 64
#define NTV 393          // ceil(V/128)
#define NT64 786         // ceil(V/64)
#define IGNORE_INDEX (-100)

typedef __attribute__((ext_vector_type(8))) short bf16x8;
typedef __attribute__((ext_vector_type(8))) u16   u16x8;
typedef __attribute__((ext_vector_type(4))) float f32x4;

__device__ __forceinline__ u16 f2bf(float f) {
  u32 u = __builtin_bit_cast(u32, f);
  u = (u + 0x7FFFu + ((u >> 16) & 1u)) >> 16;   // RNE; inputs are finite randoms
  return (u16)u;
}

// async global->LDS, 16B per lane. LDS dest must be linear in lane order.
__device__ __forceinline__ void gload_lds16(const void* g, void* l) {
  __builtin_amdgcn_global_load_lds(
      (const __attribute__((address_space(1))) u32*)(u64)g,
      (__attribute__((address_space(3))) u32*)(u32)(u64)l,
      16, 0, 0);
}

// ---------------- fp32 -> bf16 conversion (8 elems / thread) ----------------
__global__ __launch_bounds__(256) void cvt_f32_bf16(const float* __restrict__ in,
                                                    u16* __restrict__ out,
                                                    long long n) {
  long long i = ((long long)blockIdx.x * 256 + threadIdx.x) * 8;
  if (i >= n) return;
  const float4* p = (const float4*)(in + i);
  float4 a = p[0];
  float4 b = p[1];
  u16x8 o;
  o[0] = f2bf(a.x); o[1] = f2bf(a.y); o[2] = f2bf(a.z); o[3] = f2bf(a.w);
  o[4] = f2bf(b.x); o[5] = f2bf(b.y); o[6] = f2bf(b.z); o[7] = f2bf(b.w);
  *(u16x8*)(out + i) = o;
}

// ---------------- fused GEMM + partial CE ----------------
// C[n,v] = dot(X[n,:], W[v,:])  (both K-major: classic "B^T" NT GEMM)
// 128x128 tile, BK=64, 4 waves (2x2), each wave 64x64 via 4x4 x 16x16x32 MFMA.
// Epilogue: per (row, 64-col half tile) write partial max / sumexp; grab target logit.
__global__ __launch_bounds__(256) void gemm_ce(const u16* __restrict__ Xb,
                                               const u16* __restrict__ Wb,
                                               const int* __restrict__ target,
                                               float* __restrict__ pmax_out,
                                               float* __restrict__ psum_out,
                                               float* __restrict__ tgt_logit) {
  __shared__ u16 As[BM * BK];
  __shared__ u16 Bs[BN * BK];

  const int t    = threadIdx.x;
  const int w    = t >> 6;
  const int lane = t & 63;
  const int wr   = w >> 1, wc = w & 1;
  const int g    = lane >> 4, c = lane & 15;
  const int btile = blockIdx.x;            // v tile
  const int R0 = blockIdx.y * BM;
  const int C0 = btile * BN;

  f32x4 acc[4][4];
#pragma unroll
  for (int m = 0; m < 4; ++m)
#pragma unroll
    for (int n = 0; n < 4; ++n) acc[m][n] = (f32x4)0.f;

  for (int k0 = 0; k0 < H_DIM; k0 += BK) {
    // stage A tile (128x64 bf16 = 16KB): 4 x 16B per thread, linear in lane order
#pragma unroll
    for (int i = 0; i < 4; ++i) {
      int e = (i * 256 + t) * 8;           // element index in tile
      int row = e >> 6, kk = e & 63;
      gload_lds16(Xb + (size_t)(R0 + row) * H_DIM + k0 + kk, (void*)&As[e]);
    }
    // stage B tile (128x64 of W rows = output cols); clamp tail rows to V-1
#pragma unroll
    for (int i = 0; i < 4; ++i) {
      int e = (i * 256 + t) * 8;
      int row = e >> 6, kk = e & 63;
      int vg = C0 + row; if (vg > V_DIM - 1) vg = V_DIM - 1;
      gload_lds16(Wb + (size_t)vg * H_DIM + k0 + kk, (void*)&Bs[e]);
    }
    __syncthreads();   // compiler drains vmcnt before barrier -> tiles visible

#pragma unroll
    for (int h = 0; h < 2; ++h) {
      bf16x8 af[4], bfr[4];
#pragma unroll
      for (int m = 0; m < 4; ++m)
        af[m] = *(const bf16x8*)&As[(wr * 64 + m * 16 + c) * BK + h * 32 + g * 8];
#pragma unroll
      for (int n = 0; n < 4; ++n)
        bfr[n] = *(const bf16x8*)&Bs[(wc * 64 + n * 16 + c) * BK + h * 32 + g * 8];
#pragma unroll
      for (int m = 0; m < 4; ++m)
#pragma unroll
        for (int n = 0; n < 4; ++n)
          acc[m][n] = __builtin_amdgcn_mfma_f32_16x16x32_bf16(af[m], bfr[n], acc[m][n], 0, 0, 0);
    }
    __syncthreads();   // protect LDS from next iteration's staging
  }

  // ---- epilogue: per-row partial max & sumexp over this wave's 64 cols ----
  const float L2E = 1.4426950408889634f;
  const int wrow0 = R0 + wr * 64;
  const int wcol0 = C0 + wc * 64;
#pragma unroll
  for (int m = 0; m < 4; ++m) {
#pragma unroll
    for (int r = 0; r < 4; ++r) {
      int rowr = wrow0 + m * 16 + g * 4 + r;
      float vals[4];
      float vmax = -__builtin_inff();
#pragma unroll
      for (int n = 0; n < 4; ++n) {
        int col = wcol0 + n * 16 + c;
        float v = acc[m][n][r];
        vals[n] = (col < V_DIM) ? v : -__builtin_inff();
        vmax = fmaxf(vmax, vals[n]);
      }
#pragma unroll
      for (int ofs = 1; ofs < 16; ofs <<= 1) vmax = fmaxf(vmax, __shfl_xor(vmax, ofs));
      float vsum = 0.f;
#pragma unroll
      for (int n = 0; n < 4; ++n) vsum += exp2f((vals[n] - vmax) * L2E);  // -inf -> 0
#pragma unroll
      for (int ofs = 1; ofs < 16; ofs <<= 1) vsum += __shfl_xor(vsum, ofs);

      int tg = target[rowr];
      if (tg >= wcol0 && tg < wcol0 + 64) {
        int d = tg - wcol0;
        // COMPILE-TIME index into acc (rule #20: runtime index -> scratch spill)
#pragma unroll
        for (int n = 0; n < 4; ++n) {
          if ((d >> 4) == n && (d & 15) == c) tgt_logit[rowr] = acc[m][n][r];
        }
      }
      if (c == 0) {
        size_t idx = (size_t)rowr * NT64 + (size_t)btile * 2 + wc;
        pmax_out[idx] = vmax;
        psum_out[idx] = vsum;
      }
    }
  }
}

// ---------------- stage 2: merge 786 partials per row -> per-row loss ----------------
__global__ __launch_bounds__(256) void reduce_rows(const float* __restrict__ pmax_in,
                                                   const float* __restrict__ psum_in,
                                                   const float* __restrict__ tgt_logit,
                                                   const int* __restrict__ target,
                                                   float* __restrict__ loss_row) {
  const float L2E = 1.4426950408889634f;
  const float LN2 = 0.6931471805599453f;
  int t = threadIdx.x;
  int lane = t & 63;
  int row = blockIdx.x * 4 + (t >> 6);

  float m = -__builtin_inff();
  float s = 0.f;
  for (int j = lane; j < NT64; j += 64) {
    float pm = pmax_in[(size_t)row * NT64 + j];
    float ps = psum_in[(size_t)row * NT64 + j];
    float nm = fmaxf(m, pm);
    s = s * exp2f((m - nm) * L2E) + ps * exp2f((pm - nm) * L2E);
    m = nm;
  }
#pragma unroll
  for (int ofs = 1; ofs < 64; ofs <<= 1) {
    float om = __shfl_xor(m, ofs);
    float os = __shfl_xor(s, ofs);
    float nm = fmaxf(m, om);
    s = s * exp2f((m - nm) * L2E) + os * exp2f((om - nm) * L2E);
    m = nm;
  }
  if (lane == 0) {
    int tg = target[row];
    float loss = 0.f;
    if (tg != IGNORE_INDEX) {
      float lse = m + log2f(s) * LN2;
      loss = lse - tgt_logit[row];
    }
    loss_row[row] = loss;
  }
}

// ---------------- stage 3: deterministic final sum ----------------
__global__ __launch_bounds__(256) void final_sum(const float* __restrict__ loss_row,
                                                 float* __restrict__ out) {
  __shared__ float sm[256];
  int t = threadIdx.x;
  float s = 0.f;
  for (int i = t; i < N_ROWS; i += 256) s += loss_row[i];
  sm[t] = s;
  __syncthreads();
  for (int st = 128; st > 0; st >>= 1) {
    if (t < st) sm[t] += sm[t + st];
    __syncthreads();
  }
  if (t == 0) out[0] = sm[0];
}

extern "C" void kernel_launch(void* const* d_in, const int* in_sizes, int n_in,
                              void* d_out, int out_size, void* d_ws, size_t ws_size,
                              hipStream_t stream) {
  const float* x  = (const float*)d_in[0];
  const float* wt = (const float*)d_in[1];
  const int* target = (const int*)d_in[2];
  float* out = (float*)d_out;

  char* ws = (char*)d_ws;
  size_t o = 0;
  u16* Xb = (u16*)(ws + o); o += (size_t)N_ROWS * H_DIM * 2;
  u16* Wb = (u16*)(ws + o); o += (size_t)V_DIM * H_DIM * 2;
  o = (o + 255) & ~(size_t)255;
  float* pmax = (float*)(ws + o); o += (size_t)N_ROWS * NT64 * 4;
  float* psum = (float*)(ws + o); o += (size_t)N_ROWS * NT64 * 4;
  float* tgt  = (float*)(ws + o); o += (size_t)N_ROWS * 4;
  float* lrow = (float*)(ws + o); o += (size_t)N_ROWS * 4;
  if (o > ws_size) return;   // workspace too small: fail loudly (validation will flag)

  long long nX = (long long)N_ROWS * H_DIM;
  long long nW = (long long)V_DIM * H_DIM;
  cvt_f32_bf16<<<(int)((nX + 2047) / 2048), 256, 0, stream>>>(x, Xb, nX);
  cvt_f32_bf16<<<(int)((nW + 2047) / 2048), 256, 0, stream>>>(wt, Wb, nW);

  dim3 grid(NTV, N_ROWS / BM);
  gemm_ce<<<grid, 256, 0, stream>>>(Xb, Wb, target, pmax, psum, tgt);

  reduce_rows<<<N_ROWS / 4, 256, 0, stream>>>(pmax, psum, tgt, target, lrow);
  final_sum<<<1, 256, 0, stream>>>(lrow, out);
}